// Round 15
// baseline (226.594 us; speedup 1.0000x reference)
//
#include <hip/hip_runtime.h>
#include <math.h>

// Problem constants (fixed by the reference).
#define BB 4
#define SS 2048
#define DD 16
#define HH 16
#define NM 32  // Taylor moments m = 0..31

#define EXP2(x) __builtin_amdgcn_exp2f(x)
#define LOG2E 1.44269504088896340736f

__constant__ float INVFACT[NM] = {
    1.000000000e+00f, 1.000000000e+00f, 5.000000000e-01f, 1.666666667e-01f,
    4.166666667e-02f, 8.333333333e-03f, 1.388888889e-03f, 1.984126984e-04f,
    2.480158730e-05f, 2.755731922e-06f, 2.755731922e-07f, 2.505210839e-08f,
    2.087675699e-09f, 1.605904384e-10f, 1.147074560e-11f, 7.647163732e-13f,
    4.779477332e-14f, 2.811457254e-15f, 1.561920697e-16f, 8.220635247e-18f,
    4.110317623e-19f, 1.957294106e-20f, 8.896791392e-22f, 3.868170171e-23f,
    1.611737571e-24f, 6.446950284e-26f, 2.479596263e-27f, 9.183689864e-29f,
    3.279889237e-30f, 1.130996289e-31f, 3.769987629e-33f, 1.216125042e-34f};

#define UNPACK16(X4, XR)                                                   \
  const float4 x0_ = (X4)[0], x1_ = (X4)[1], x2_ = (X4)[2], x3_ = (X4)[3]; \
  const float XR[16] = {x0_.x, x0_.y, x0_.z, x0_.w, x1_.x, x1_.y, x1_.z,   \
                        x1_.w, x2_.x, x2_.y, x2_.z, x2_.w, x3_.x, x3_.y,   \
                        x3_.z, x3_.w};

// ---------------------------------------------------------------------------
// Kernel M: per-(bh, j-block) moment sums with 1/m! PREFOLDED:
// MT[bh][jb][m]    = (sum_j k_j^m) / m!
// MT[bh][jb][32+m] = (sum_j k_j^m v_j) / m!     (j in block jb, m = 0..31)
// grid = 64 bh x 4 sub = 256 blocks x 256 thr (R11-identical math).
// ALSO initializes out[b][s][d] = b_out[d] (bias): out = 32768 float4 total,
// 128 float4 per block (threads t < 128). Kernel-boundary ordering makes the
// init visible to the attention kernel's atomics.
// ---------------------------------------------------------------------------
__global__ __launch_bounds__(256) void moment_kernel(
    const float* __restrict__ x, const float* __restrict__ w_qkv,
    const float* __restrict__ b_qkv, const float* __restrict__ b_out,
    float* __restrict__ MT, float* __restrict__ out) {
  __shared__ float kl[512];
  __shared__ float vl[512];
  const int blk = blockIdx.x;
  const int sub = blk & 3;
  const int bh = blk >> 2;
  const int b = bh >> 4, h = bh & 15;
  const int t = threadIdx.x;

  // --- out-init: block blk covers float4 indices [blk*128, blk*128+128) ---
  if (t < 128) {
    const float4 bias4[4] = {
        {b_out[0], b_out[1], b_out[2], b_out[3]},
        {b_out[4], b_out[5], b_out[6], b_out[7]},
        {b_out[8], b_out[9], b_out[10], b_out[11]},
        {b_out[12], b_out[13], b_out[14], b_out[15]}};
    float4* out4 = (float4*)out;
    const int idx4 = blk * 128 + t;  // max 255*128+127 = 32767: in bounds
    out4[idx4] = bias4[idx4 & 3];
  }

  float wk[16], wv[16];  // block-uniform -> scalar loads
#pragma unroll
  for (int i = 0; i < 16; ++i) {
    wk[i] = w_qkv[i * 48 + 16 + h];
    wv[i] = w_qkv[i * 48 + 32 + h];
  }
  const float bk = b_qkv[16 + h], bv = b_qkv[32 + h];

#pragma unroll
  for (int rr = 0; rr < 2; ++rr) {
    const int jl = rr * 256 + t;  // local j 0..511
    const int j = sub * 512 + jl;
    const float4* X4 = (const float4*)(x + ((size_t)b * SS + j) * DD);
    UNPACK16(X4, xr);
    float k = bk, v = bv;
#pragma unroll
    for (int i = 0; i < 16; ++i) {
      k = fmaf(xr[i], wk[i], k);
      v = fmaf(xr[i], wv[i], v);
    }
    kl[jl] = k;
    vl[jl] = v;
  }
  __syncthreads();

  const int m = t & 31;
  const int jl = t >> 5;        // 0..7
  const int jb = sub * 8 + jl;  // global j-block 0..31
  float s = 0.f, tv = 0.f;
  const int base = jl * 64;
  for (int u = 0; u < 64; ++u) {
    const float k = kl[base + u];  // broadcast across the 32 m-threads
    const float v = vl[base + u];
    const float k2 = k * k, k4 = k2 * k2, k8 = k4 * k4, k16 = k8 * k8;
    float p = (m & 1) ? k : 1.f;
    p *= (m & 2) ? k2 : 1.f;
    p *= (m & 4) ? k4 : 1.f;
    p *= (m & 8) ? k8 : 1.f;
    p *= (m & 16) ? k16 : 1.f;
    s += p;
    tv = fmaf(p, v, tv);
  }
  const float c = INVFACT[m];
  float* row = MT + ((size_t)bh * 32 + jb) * 64;
  row[m] = s * c;
  row[32 + m] = tv * c;
}

// ---------------------------------------------------------------------------
// Kernel B: attention via moments + exact diagonal, with the output
// projection fused via atomics: out[b,s,d] += ao * w_out[h][d].
// grid = 64 bh x 32 qb = 2048 blocks x 64 thr (one wave) -- R11 grid shape.
// ---------------------------------------------------------------------------
__global__ __launch_bounds__(64) void attn_kernel(
    const float* __restrict__ x, const float* __restrict__ w_qkv,
    const float* __restrict__ b_qkv, const float* __restrict__ MT,
    const float* __restrict__ w_out, float* __restrict__ out) {
  __shared__ float kd[64], vd[64], bc[64];
  const int blk = blockIdx.x;
  const int qb = blk & 31;
  const int bh = blk >> 5;
  const int b = bh >> 4, h = bh & 15;
  const int lane = threadIdx.x;

  float wq[16], wk[16], wv[16];  // wave-uniform -> scalar loads
#pragma unroll
  for (int i = 0; i < 16; ++i) {
    wq[i] = w_qkv[i * 48 + h];
    wk[i] = w_qkv[i * 48 + 16 + h];
    wv[i] = w_qkv[i * 48 + 32 + h];
  }

  const int i0 = qb * 64 + lane;
  const float4* X4 = (const float4*)(x + ((size_t)b * SS + i0) * DD);
  UNPACK16(X4, xr);
  float q = b_qkv[h], k = b_qkv[16 + h], v = b_qkv[32 + h];
#pragma unroll
  for (int i = 0; i < 16; ++i) {
    q = fmaf(xr[i], wq[i], q);
    k = fmaf(xr[i], wk[i], k);
    v = fmaf(xr[i], wv[i], v);
  }
  kd[lane] = k;
  vd[lane] = v;
  const float qs = q * LOG2E;

  // Prefix-sum the (prefolded) moment table over jb < qb.
  // bc layout: bc[2m] = S_m/m!, bc[2m+1] = T_m/m!.
  if (qb > 0) {
    const float* mtb = MT + (size_t)bh * 32 * 64 + lane;
    float acc = 0.f;
#pragma unroll 4
    for (int jb = 0; jb < qb; ++jb) acc += mtb[jb * 64];  // coalesced
    const int slot = (lane < 32) ? (2 * lane) : (2 * (lane - 32) + 1);
    bc[slot] = acc;
  }
  __syncthreads();

  float num = 0.f, den = 0.f;
  if (qb > 0) {
    const float2* bc2 = (const float2*)bc;
    float p = 1.f;  // q^m
#pragma unroll
    for (int m = 0; m < NM; ++m) {
      const float2 st = bc2[m];  // broadcast read
      den = fmaf(p, st.x, den);
      num = fmaf(p, st.y, num);
      p *= q;
    }
  }

  // Exact diagonal block (lane-predicated: j_local <= lane).
  float ld = 0.f, ad = 0.f;
  const float4* kd4 = (const float4*)kd;
  const float4* vd4 = (const float4*)vd;
#pragma unroll
  for (int g = 0; g < 16; ++g) {
    const float4 k4 = kd4[g], v4 = vd4[g];
    const int jj = 4 * g;
    float e;
    e = EXP2(qs * k4.x); e = (jj + 0 <= lane) ? e : 0.f; ld += e; ad = fmaf(e, v4.x, ad);
    e = EXP2(qs * k4.y); e = (jj + 1 <= lane) ? e : 0.f; ld += e; ad = fmaf(e, v4.y, ad);
    e = EXP2(qs * k4.z); e = (jj + 2 <= lane) ? e : 0.f; ld += e; ad = fmaf(e, v4.z, ad);
    e = EXP2(qs * k4.w); e = (jj + 3 <= lane) ? e : 0.f; ld += e; ad = fmaf(e, v4.w, ad);
  }

  const float ao = (ad + num) / (ld + den);

  // Fused projection: out[b, i0, d] += ao * w_out[h][d] (bias pre-added).
  float* orow = out + ((size_t)b * SS + i0) * DD;
#pragma unroll
  for (int d = 0; d < DD; ++d) {
    atomicAdd(orow + d, ao * w_out[h * DD + d]);  // w_out row: scalar loads
  }
}

// ---------------------------------------------------------------------------
extern "C" void kernel_launch(void* const* d_in, const int* in_sizes, int n_in,
                              void* d_out, int out_size, void* d_ws,
                              size_t ws_size, hipStream_t stream) {
  const float* x = (const float*)d_in[0];       // [B,S,D]
  const float* w_qkv = (const float*)d_in[1];   // [D, 3D]
  const float* b_qkv = (const float*)d_in[2];   // [3D]
  const float* w_out = (const float*)d_in[3];   // [D, D]
  const float* b_out = (const float*)d_in[4];   // [D]
  float* out = (float*)d_out;                   // [B,S,D] fp32

  float* MT = (float*)d_ws;  // [64 bh][32 jb][64] prefolded moments (512 KB)

  moment_kernel<<<256, 256, 0, stream>>>(x, w_qkv, b_qkv, b_out, MT, out);
  attn_kernel<<<2048, 64, 0, stream>>>(x, w_qkv, b_qkv, MT, w_out, out);
}

// Round 16
// 79.529 us; speedup vs baseline: 2.8492x; 2.8492x over previous
//
#include <hip/hip_runtime.h>
#include <math.h>

// Problem constants (fixed by the reference).
#define BB 4
#define SS 2048
#define DD 16
#define HH 16
#define NM 32  // Taylor moments m = 0..31

#define EXP2(x) __builtin_amdgcn_exp2f(x)
#define LOG2E 1.44269504088896340736f

__constant__ float INVFACT[NM] = {
    1.000000000e+00f, 1.000000000e+00f, 5.000000000e-01f, 1.666666667e-01f,
    4.166666667e-02f, 8.333333333e-03f, 1.388888889e-03f, 1.984126984e-04f,
    2.480158730e-05f, 2.755731922e-06f, 2.755731922e-07f, 2.505210839e-08f,
    2.087675699e-09f, 1.605904384e-10f, 1.147074560e-11f, 7.647163732e-13f,
    4.779477332e-14f, 2.811457254e-15f, 1.561920697e-16f, 8.220635247e-18f,
    4.110317623e-19f, 1.957294106e-20f, 8.896791392e-22f, 3.868170171e-23f,
    1.611737571e-24f, 6.446950284e-26f, 2.479596263e-27f, 9.183689864e-29f,
    3.279889237e-30f, 1.130996289e-31f, 3.769987629e-33f, 1.216125042e-34f};

#define UNPACK16(X4, XR)                                                   \
  const float4 x0_ = (X4)[0], x1_ = (X4)[1], x2_ = (X4)[2], x3_ = (X4)[3]; \
  const float XR[16] = {x0_.x, x0_.y, x0_.z, x0_.w, x1_.x, x1_.y, x1_.z,   \
                        x1_.w, x2_.x, x2_.y, x2_.z, x2_.w, x3_.x, x3_.y,   \
                        x3_.z, x3_.w};

// ---------------------------------------------------------------------------
// Kernel M: per-(bh, j-block) moment sums. MT[bh][jb][m] = sum_j k_j^m,
// MT[bh][jb][32+m] = sum_j k_j^m v_j  (j in block jb, m = 0..31).
// grid = 64 bh x 4 sub = 256 blocks x 256 thr. Block covers 8 j-blocks
// (512 j's): stage k,v in LDS, then thread (jl = t>>5, m = t&31) reduces
// its j-block. k^m via exp-by-squaring with per-lane bit selects.
// ---------------------------------------------------------------------------
__global__ __launch_bounds__(256) void moment_kernel(
    const float* __restrict__ x, const float* __restrict__ w_qkv,
    const float* __restrict__ b_qkv, float* __restrict__ MT) {
  __shared__ float kl[512];
  __shared__ float vl[512];
  const int blk = blockIdx.x;
  const int sub = blk & 3;
  const int bh = blk >> 2;
  const int b = bh >> 4, h = bh & 15;
  const int t = threadIdx.x;

  float wk[16], wv[16];  // block-uniform -> scalar loads
#pragma unroll
  for (int i = 0; i < 16; ++i) {
    wk[i] = w_qkv[i * 48 + 16 + h];
    wv[i] = w_qkv[i * 48 + 32 + h];
  }
  const float bk = b_qkv[16 + h], bv = b_qkv[32 + h];

#pragma unroll
  for (int rr = 0; rr < 2; ++rr) {
    const int jl = rr * 256 + t;  // local j 0..511
    const int j = sub * 512 + jl;
    const float4* X4 = (const float4*)(x + ((size_t)b * SS + j) * DD);
    UNPACK16(X4, xr);
    float k = bk, v = bv;
#pragma unroll
    for (int i = 0; i < 16; ++i) {
      k = fmaf(xr[i], wk[i], k);
      v = fmaf(xr[i], wv[i], v);
    }
    kl[jl] = k;
    vl[jl] = v;
  }
  __syncthreads();

  const int m = t & 31;
  const int jl = t >> 5;        // 0..7
  const int jb = sub * 8 + jl;  // global j-block 0..31
  float s = 0.f, tv = 0.f;
  const int base = jl * 64;
  for (int u = 0; u < 64; ++u) {
    const float k = kl[base + u];  // broadcast across the 32 m-threads
    const float v = vl[base + u];
    const float k2 = k * k, k4 = k2 * k2, k8 = k4 * k4, k16 = k8 * k8;
    float p = (m & 1) ? k : 1.f;
    p *= (m & 2) ? k2 : 1.f;
    p *= (m & 4) ? k4 : 1.f;
    p *= (m & 8) ? k8 : 1.f;
    p *= (m & 16) ? k16 : 1.f;
    s += p;
    tv = fmaf(p, v, tv);
  }
  float* row = MT + ((size_t)bh * 32 + jb) * 64;
  row[m] = s;
  row[32 + m] = tv;
}

// ---------------------------------------------------------------------------
// Kernel B: attention via moments + exact diagonal.
// grid = 64 bh x 32 qb = 2048 blocks x 64 thr (one wave). Lane = query
// i = qb*64+lane. Full blocks jb < qb contribute through prefix-summed
// moments (32 fma per query); the diagonal block is exact exp2, lane-
// predicated. Writes final a/l to AO[bh][s].
// ---------------------------------------------------------------------------
__global__ __launch_bounds__(64) void attn_kernel(
    const float* __restrict__ x, const float* __restrict__ w_qkv,
    const float* __restrict__ b_qkv, const float* __restrict__ MT,
    float* __restrict__ AO) {
  __shared__ float kd[64], vd[64], bc[64];
  const int blk = blockIdx.x;
  const int qb = blk & 31;
  const int bh = blk >> 5;
  const int b = bh >> 4, h = bh & 15;
  const int lane = threadIdx.x;

  float wq[16], wk[16], wv[16];  // wave-uniform -> scalar loads
#pragma unroll
  for (int i = 0; i < 16; ++i) {
    wq[i] = w_qkv[i * 48 + h];
    wk[i] = w_qkv[i * 48 + 16 + h];
    wv[i] = w_qkv[i * 48 + 32 + h];
  }

  const int i0 = qb * 64 + lane;
  const float4* X4 = (const float4*)(x + ((size_t)b * SS + i0) * DD);
  UNPACK16(X4, xr);
  float q = b_qkv[h], k = b_qkv[16 + h], v = b_qkv[32 + h];
#pragma unroll
  for (int i = 0; i < 16; ++i) {
    q = fmaf(xr[i], wq[i], q);
    k = fmaf(xr[i], wk[i], k);
    v = fmaf(xr[i], wv[i], v);
  }
  kd[lane] = k;
  vd[lane] = v;
  const float qs = q * LOG2E;

  // Prefix-sum the moment table over jb < qb; fold in 1/m!.
  // bc layout: bc[2m] = S_m/m!, bc[2m+1] = T_m/m!.
  if (qb > 0) {
    const float* mtb = MT + (size_t)bh * 32 * 64 + lane;
    float acc = 0.f;
    for (int jb = 0; jb < qb; ++jb) acc += mtb[jb * 64];  // coalesced
    const float c = INVFACT[lane & 31];
    const int slot = (lane < 32) ? (2 * lane) : (2 * (lane - 32) + 1);
    bc[slot] = acc * c;
  }
  __syncthreads();

  float num = 0.f, den = 0.f;
  if (qb > 0) {
    const float2* bc2 = (const float2*)bc;
    float p = 1.f;  // q^m
#pragma unroll
    for (int m = 0; m < NM; ++m) {
      const float2 st = bc2[m];  // broadcast read
      den = fmaf(p, st.x, den);
      num = fmaf(p, st.y, num);
      p *= q;
    }
  }

  // Exact diagonal block (lane-predicated: j_local <= lane).
  float ld = 0.f, ad = 0.f;
  const float4* kd4 = (const float4*)kd;
  const float4* vd4 = (const float4*)vd;
#pragma unroll
  for (int g = 0; g < 16; ++g) {
    const float4 k4 = kd4[g], v4 = vd4[g];
    const int jj = 4 * g;
    float e;
    e = EXP2(qs * k4.x); e = (jj + 0 <= lane) ? e : 0.f; ld += e; ad = fmaf(e, v4.x, ad);
    e = EXP2(qs * k4.y); e = (jj + 1 <= lane) ? e : 0.f; ld += e; ad = fmaf(e, v4.y, ad);
    e = EXP2(qs * k4.z); e = (jj + 2 <= lane) ? e : 0.f; ld += e; ad = fmaf(e, v4.z, ad);
    e = EXP2(qs * k4.w); e = (jj + 3 <= lane) ? e : 0.f; ld += e; ad = fmaf(e, v4.w, ad);
  }

  AO[(size_t)bh * SS + i0] = (ad + num) / (ld + den);  // coalesced
}

// ---------------------------------------------------------------------------
// Kernel C: out = AO @ w_out + b_out. 512 blocks x 256 thr; block = 16 rows.
// ---------------------------------------------------------------------------
__global__ __launch_bounds__(256) void proj_kernel(
    const float* __restrict__ AO, const float* __restrict__ w,
    const float* __restrict__ bias, float* __restrict__ out) {
  __shared__ float wct[DD * 68];  // column d at wct[d*68 + i]
  __shared__ float aol[256];      // aol[row_l*16 + h]
  __shared__ float bs[DD];
  const int t = threadIdx.x;
  const int b = blockIdx.x >> 7;  // 128 blocks per batch
  const int s_base = (blockIdx.x * 16) & (SS - 1);

  wct[(t & 15) * 68 + (t >> 4)] = w[t];
  if (t < DD) bs[t] = bias[t];
  {
    const int h = t >> 4, row_l = t & 15;
    const int bh = b * HH + h;
    aol[row_l * 16 + h] = AO[(size_t)bh * SS + s_base + row_l];
  }
  __syncthreads();

  const int row_l = t >> 4, d = t & 15;
  const float4* ao4 = (const float4*)aol;
  const float4* wc4 = (const float4*)wct;

  float y = bs[d];
#pragma unroll
  for (int g = 0; g < 4; ++g) {
    const float4 xv = ao4[row_l * 4 + g];
    const float4 wv = wc4[d * 17 + g];
    y = fmaf(xv.x, wv.x, y);
    y = fmaf(xv.y, wv.y, y);
    y = fmaf(xv.z, wv.z, y);
    y = fmaf(xv.w, wv.w, y);
  }
  out[(size_t)blockIdx.x * 256 + t] = y;
}

// ---------------------------------------------------------------------------
extern "C" void kernel_launch(void* const* d_in, const int* in_sizes, int n_in,
                              void* d_out, int out_size, void* d_ws,
                              size_t ws_size, hipStream_t stream) {
  const float* x = (const float*)d_in[0];       // [B,S,D]
  const float* w_qkv = (const float*)d_in[1];   // [D, 3D]
  const float* b_qkv = (const float*)d_in[2];   // [3D]
  const float* w_out = (const float*)d_in[3];   // [D, D]
  const float* b_out = (const float*)d_in[4];   // [D]
  float* out = (float*)d_out;                   // [B,S,D] fp32

  float* ws = (float*)d_ws;
  float* MT = ws;                     // [64 bh][32 jb][64] moments (512 KB)
  float* AO = ws + 64 * 32 * 64;      // [64 bh][2048 s] attention out (512 KB)

  moment_kernel<<<256, 256, 0, stream>>>(x, w_qkv, b_qkv, MT);
  attn_kernel<<<2048, 64, 0, stream>>>(x, w_qkv, b_qkv, MT, AO);
  proj_kernel<<<512, 256, 0, stream>>>(AO, w_out, b_out, out);
}